// Round 3
// baseline (103.164 us; speedup 1.0000x reference)
//
#include <hip/hip_runtime.h>
#include <math.h>

// Problem constants (fixed by setup_inputs)
#define B_N 2
#define A_N 16384
#define G_N 24
#define C_N 8
#define NV  16          // polygon vertex capacity == reference MAXV
#define BPI 256         // blocks per image in k_main (A_N / 64)

// ---- workspace layout (bytes) ----
#define OFF_GTKEY  0                          // 48 u64 = 384 B (memset to 0)
#define OFF_AKEY   384                        // 32768 u64 = 256 KiB
#define OFF_PART   (384 + B_N * A_N * 8)      // 512 * 4 floats = 8 KiB

// ---- ordered-float key helpers (max with first-index tiebreak) ----
__device__ inline unsigned int fmap(float v) {
    unsigned int u = __float_as_uint(v);
    return (u & 0x80000000u) ? ~u : (u | 0x80000000u);
}
__device__ inline float funmap(unsigned int u) {
    unsigned int bits = (u & 0x80000000u) ? (u ^ 0x80000000u) : ~u;
    return __uint_as_float(bits);
}
__device__ inline unsigned long long mkkey(float v, int idx) {
    return ((unsigned long long)fmap(v) << 32) |
           (unsigned long long)(0xFFFFFFFFu - (unsigned int)idx);
}
__device__ inline float key_val(unsigned long long k) { return funmap((unsigned int)(k >> 32)); }
__device__ inline int   key_idx(unsigned long long k) { return (int)(0xFFFFFFFFu - (unsigned int)k); }

// ---- loss pieces shared by k_main and k_fix (identical codegen → exact deltas) ----
__device__ inline float smoothl1(float x) {
    const float beta = 1.0f / 9.0f;
    float d = fabsf(x);
    return (d < beta) ? (0.5f * d * d / beta) : (d - 0.5f * beta);
}
__device__ inline float balancedl1(float x) {
    const float bb  = 5.049647464412945f;          // e^1.8 - 1
    const float alb = 0.5f / 5.049647464412945f;   // al / b
    const float gab = 0.9f / 5.049647464412945f;   // ga / b
    float d = fabsf(x);
    if (d < 0.5f)
        return alb * (bb * d + 1.0f) * logf(bb * d / 0.5f + 1.0f) - 0.5f * d;
    return 0.9f * d + gab - 0.25f;
}
__device__ inline float focal_pos(const float* cr, int lab) {
    float s = 0.0f;
#pragma unroll
    for (int c = 0; c < C_N; c++) {
        float p = fminf(fmaxf(cr[c], 1e-4f), 0.9999f);
        if (c == lab) s += 0.25f * (1.0f - p) * (1.0f - p) * (-logf(p + 1e-6f));
        else          s += 0.75f * p * p * (-logf(1.0f - p + 1e-6f));
    }
    return s;
}
__device__ inline float focal_neg(const float* cr) {
    float s = 0.0f;
#pragma unroll
    for (int c = 0; c < C_N; c++) {
        float p = fminf(fmaxf(cr[c], 1e-4f), 0.9999f);
        s += 0.75f * p * p * (-logf(1.0f - p + 1e-6f));
    }
    return s;
}
__device__ inline float reg_loss(const float* rr, const float* ar, const float* annr) {
    float acx = ar[0], acy = ar[1], aw = ar[2], ah = ar[3], ath = ar[4];
    float aw1 = fmaxf(aw, 1.0f), ah1 = fmaxf(ah, 1.0f);
    float gw1 = fmaxf(annr[2], 1.0f), gh1 = fmaxf(annr[3], 1.0f);
    float t1 = 10.0f * (annr[0] - acx) / aw1;
    float t2 = 10.0f * (annr[1] - acy) / ah1;
    float t3 = 5.0f * logf(gw1 / aw1);
    float t4 = 5.0f * logf(gh1 / ah1);
    float ta = tanf(ath);
    float t5 = 15.0f * (tanf(annr[4]) - ta);
    float p0 = rr[0], p1 = rr[1], p2 = rr[2], p3 = rr[3], p4 = rr[4];
    float tg = p4 / 15.0f + ta;
    if (fabsf(tg) < 1e-4f) tg = (tg < 0.0f) ? -1e-4f : 1e-4f;
    float t22 = 15.0f * (-1.0f / tg - ta);
    float l1 = smoothl1(t1 - p0), l2 = smoothl1(t2 - p1);
    float l3 = smoothl1(t3 - p2), l4 = smoothl1(t4 - p3);
    float l5 = smoothl1(t3 - p3), l6 = smoothl1(t4 - p2);
    float l7 = smoothl1(t5 - p4), l8 = smoothl1(t5 - t22);
    return fminf(l1 + l2 + l3 + l4 + l7, l1 + l2 + l5 + l6 + l8);
}
__device__ inline float lmk_loss(const float* lk, const float* ar, const float* lr) {
    float acx = ar[0], acy = ar[1];
    float aw1 = fmaxf(ar[2], 1.0f), ah1 = fmaxf(ar[3], 1.0f);
    return balancedl1(lk[0] - 10.0f * (lr[0] - acx) / aw1)
         + balancedl1(lk[1] - 10.0f * (lr[1] - acy) / ah1)
         + balancedl1(lk[2] - 10.0f * (lr[2] - acx) / aw1)
         + balancedl1(lk[3] - 10.0f * (lr[3] - acy) / ah1);
}

// ---- K1: per-anchor assign (gate-mask + compacted clip) fused with provisional loss ----
__global__ __launch_bounds__(64) void k_main(
    const float* __restrict__ cls, const float* __restrict__ reg,
    const float* __restrict__ anch, const float* __restrict__ ann,
    const float* __restrict__ lmk, const float* __restrict__ ls,
    unsigned long long* __restrict__ gtkey, unsigned long long* __restrict__ akey,
    float* __restrict__ partials)
{
    // polygon buffers: [buf][coord][vert][lane]; vert stride 64 floats => bank = lane%32 (conflict-free)
    __shared__ float pb[2][2][NV][64];
    __shared__ float gcor[G_N][10];   // x0..x3, y0..y3, w*h  (stride 10 spreads banks under divergent g)
    __shared__ float gsq[G_N][5];     // min-area-square x1,y1,x2,y2,area
    __shared__ float glab[G_N];

    const int tid = threadIdx.x;
    const int b   = blockIdx.x >> 8;                 // BPI = 256 blocks per image
    const int a   = ((blockIdx.x & (BPI - 1)) << 6) | tid;
    const size_t idx = (size_t)b * A_N + a;
    const float* annb = ann + (size_t)b * G_N * 6;

    // stage gt geometry once per block (lanes 0..23)
    if (tid < G_N) {
        const float* annr = annb + tid * 6;
        float gcx = annr[0], gcy = annr[1], gw = annr[2], gh = annr[3], gth = annr[4];
        glab[tid] = annr[5];
        float sg = fmaxf(gw, gh);
        float gx1 = gcx - sg * 0.5f, gy1 = gcy - sg * 0.5f;
        float gx2 = gcx + sg * 0.5f, gy2 = gcy + sg * 0.5f;
        gsq[tid][0] = gx1; gsq[tid][1] = gy1; gsq[tid][2] = gx2; gsq[tid][3] = gy2;
        gsq[tid][4] = (gx2 - gx1) * (gy2 - gy1);
        float c2 = cosf(gth), s2 = sinf(gth);
        const float dxs[4] = {-0.5f, 0.5f, 0.5f, -0.5f};
        const float dys[4] = {-0.5f, -0.5f, 0.5f, 0.5f};
#pragma unroll
        for (int k = 0; k < 4; k++) {
            float ex = dxs[k] * gw, ey = dys[k] * gh;
            gcor[tid][k]     = gcx + ex * c2 - ey * s2;
            gcor[tid][4 + k] = gcy + ex * s2 + ey * c2;
        }
        gcor[tid][8] = gw * gh;
    }
    // guarantee write: all-zero gt columns must resolve to argmax anchor 0 (reference semantics)
    if (a == 0) {
        for (int g = 0; g < G_N; g++)
            atomicMax(&gtkey[b * G_N + g], mkkey(0.0f, 0));
    }
    __syncthreads();

    // uniform valid mask / first valid gt
    unsigned int validmask = 0;
    for (int g = 0; g < G_N; g++)
        if (glab[g] != -1.0f) validmask |= (1u << g);
    int first_valid = validmask ? (__ffs((int)validmask) - 1) : -1;

    const float* ar = anch + idx * 5;
    float acx = ar[0], acy = ar[1], aw = ar[2], ah = ar[3], ath = ar[4];

    // anchor min-area square
    float sa = fmaxf(aw, ah);
    float ax1 = acx - sa * 0.5f, ay1 = acy - sa * 0.5f;
    float ax2 = acx + sa * 0.5f, ay2 = acy + sa * 0.5f;
    float areaA = (ax2 - ax1) * (ay2 - ay1);

    // gate phase: uniform loop over valid gts, build per-lane pass mask
    unsigned int mask = 0;
    for (unsigned int vm = validmask; vm; vm &= vm - 1) {
        int g = __ffs((int)vm) - 1;
        float gx1 = gsq[g][0], gy1 = gsq[g][1], gx2 = gsq[g][2], gy2 = gsq[g][3];
        float iw = fmaxf(fminf(ax2, gx2) - fmaxf(ax1, gx1), 0.0f);
        float ih = fmaxf(fminf(ay2, gy2) - fmaxf(ay1, gy1), 0.0f);
        float inter0 = iw * ih;
        float ind = inter0 / fmaxf(areaA + gsq[g][4] - inter0, 1e-9f);
        if (ind >= 0.1f) mask |= (1u << g);
    }

    // anchor corners once (registers, static indexing)
    float c1 = cosf(ath), s1 = sinf(ath);
    float axk[4], ayk[4];
    {
        const float dxs[4] = {-0.5f, 0.5f, 0.5f, -0.5f};
        const float dys[4] = {-0.5f, -0.5f, 0.5f, 0.5f};
#pragma unroll
        for (int k = 0; k < 4; k++) {
            float dx = dxs[k] * aw, dy = dys[k] * ah;
            axk[k] = acx + dx * c1 - dy * s1;
            ayk[k] = acy + dx * s1 + dy * c1;
        }
    }
    float areaWH = aw * ah;

    // row key: max over zero-valued entries is just the first valid g
    unsigned long long rowkey = (first_valid >= 0) ? mkkey(0.0f, first_valid) : 0ull;

    // clip phase: per-lane compacted list of passing gts (no trig here)
    while (__any(mask != 0)) {
        if (mask) {
            int g = __ffs((int)mask) - 1;
            mask &= mask - 1;
            float p2x[4], p2y[4];
#pragma unroll
            for (int k = 0; k < 4; k++) {
                p2x[k] = gcor[g][k];
                p2y[k] = gcor[g][4 + k];
                pb[0][0][k][tid] = axk[k];
                pb[0][1][k][tid] = ayk[k];
            }
            int n = 4, cb = 0;
#pragma unroll
            for (int e = 0; e < 4; e++) {
                float apx = p2x[e], apy = p2y[e];
                float dx = p2x[(e + 1) & 3] - apx, dy = p2y[(e + 1) & 3] - apy;
                int m = 0, nb = cb ^ 1;
                for (int i = 0; i < n; i++) {
                    float cx_ = pb[cb][0][i][tid], cy_ = pb[cb][1][i][tid];
                    int j = (i + 1 >= n) ? 0 : (i + 1);
                    float nx_ = pb[cb][0][j][tid], ny_ = pb[cb][1][j][tid];
                    float sc = dx * (cy_ - apy) - dy * (cx_ - apx);
                    float sn = dx * (ny_ - apy) - dy * (nx_ - apx);
                    bool ci = (sc >= 0.0f), niv = (sn >= 0.0f);
                    if (ci) {
                        if (m < NV) { pb[nb][0][m][tid] = cx_; pb[nb][1][m][tid] = cy_; }
                        m++;
                    }
                    if (ci != niv) {
                        float den = sc - sn;
                        float t = sc / ((den == 0.0f) ? 1.0f : den);
                        if (m < NV) {
                            pb[nb][0][m][tid] = cx_ + t * (nx_ - cx_);
                            pb[nb][1][m][tid] = cy_ + t * (ny_ - cy_);
                        }
                        m++;
                    }
                }
                n = (m > NV) ? NV : m;
                cb = nb;
            }
            float ssum = 0.0f;
            for (int i = 0; i < n; i++) {
                int j = (i + 1 >= n) ? 0 : (i + 1);
                ssum += pb[cb][0][i][tid] * pb[cb][1][j][tid]
                      - pb[cb][0][j][tid] * pb[cb][1][i][tid];
            }
            float interA = 0.5f * fabsf(ssum);
            float uni = areaWH + gcor[g][8] - interA;
            float val = interA / fmaxf(uni, 1e-9f);

            unsigned long long k = mkkey(val, g);
            if (k > rowkey) rowkey = k;
            if (val > 0.0f) atomicMax(&gtkey[b * G_N + g], mkkey(val, a));
        }
    }

    akey[idx] = rowkey;                              // plain store, no atomic

    // provisional loss (pos = iou_max >= 0.5; forced fixes applied in k_fix)
    float iou_max = key_val(rowkey);                 // NaN when no valid gt -> both branches false
    int gmax = key_idx(rowkey);
    const float* annr = annb + gmax * 6;
    const float* cr = cls + idx * C_N;
    float cls_sum = 0.0f, reg_sum = 0.0f, lmk_sum = 0.0f;
    int pc = 0;
    if (iou_max >= 0.5f) {
        pc = 1;
        cls_sum = focal_pos(cr, (int)annr[5]);
        reg_sum = reg_loss(reg + idx * 5, ar, annr);
        lmk_sum = lmk_loss(lmk + idx * 4, ar, ls + (size_t)(b * G_N + gmax) * 4);
    } else if (iou_max < 0.4f) {
        cls_sum = focal_neg(cr);
    }

    float fpc = (float)pc;
    for (int off = 32; off; off >>= 1) {
        cls_sum += __shfl_down(cls_sum, off);
        reg_sum += __shfl_down(reg_sum, off);
        lmk_sum += __shfl_down(lmk_sum, off);
        fpc     += __shfl_down(fpc, off);
    }
    if (tid == 0) {
        float* p = partials + (size_t)blockIdx.x * 4;
        p[0] = cls_sum; p[1] = reg_sum; p[2] = lmk_sum; p[3] = fpc;
    }
}

// ---- K2: double-precision partial reduction + force-positive deltas + finalize ----
__global__ __launch_bounds__(128) void k_fix(
    const float* __restrict__ cls, const float* __restrict__ reg,
    const float* __restrict__ anch, const float* __restrict__ ann,
    const float* __restrict__ lmk, const float* __restrict__ ls,
    const unsigned long long* __restrict__ gtkey, const unsigned long long* __restrict__ akey,
    const float* __restrict__ partials, float* __restrict__ out)
{
    __shared__ float res[B_N][3];
    const int tid = threadIdx.x;
    const int b = tid >> 6, lane = tid & 63;

    double s0 = 0.0, s1 = 0.0, s2 = 0.0, s3 = 0.0;
    for (int r = lane; r < BPI; r += 64) {
        const float* p = partials + (size_t)(b * BPI + r) * 4;
        s0 += p[0]; s1 += p[1]; s2 += p[2]; s3 += p[3];
    }
    for (int off = 32; off; off >>= 1) {
        s0 += __shfl_down(s0, off);
        s1 += __shfl_down(s1, off);
        s2 += __shfl_down(s2, off);
        s3 += __shfl_down(s3, off);
    }

    const float* annb = ann + (size_t)b * G_N * 6;
    float dc = 0.0f, dr = 0.0f, dl = 0.0f; int dn = 0;
    if (lane < G_N) {
        bool valid = annb[lane * 6 + 5] != -1.0f;
        unsigned long long k = gtkey[b * G_N + lane];
        int fa = key_idx(k);
        bool force = valid && (key_val(k) < 0.5f);
        if (force) {                                 // dedupe: lowest forcing g claims the anchor
            for (int g2 = 0; g2 < lane; g2++) {
                if (annb[g2 * 6 + 5] == -1.0f) continue;
                unsigned long long k2 = gtkey[b * G_N + g2];
                if (key_val(k2) < 0.5f && key_idx(k2) == fa) { force = false; break; }
            }
        }
        if (force) {
            size_t fidx = (size_t)b * A_N + fa;
            unsigned long long ak = akey[fidx];
            float im = key_val(ak);
            if (!(im >= 0.5f)) {                     // not already positive
                dn = 1;
                int gm = key_idx(ak);
                const float* cr = cls + fidx * C_N;
                const float* annr = annb + gm * 6;
                const float* arr = anch + fidx * 5;
                dc = focal_pos(cr, (int)annr[5]);
                if (im < 0.4f) dc -= focal_neg(cr);  // remove provisional negative contribution
                dr = reg_loss(reg + fidx * 5, arr, annr);
                dl = lmk_loss(lmk + fidx * 4, arr, ls + (size_t)(b * G_N + gm) * 4);
            }
        }
    }
    float fdn = (float)dn;
    for (int off = 32; off; off >>= 1) {
        dc  += __shfl_down(dc, off);
        dr  += __shfl_down(dr, off);
        dl  += __shfl_down(dl, off);
        fdn += __shfl_down(fdn, off);
    }
    if (lane == 0) {
        bool has_gt = false;
        for (int g = 0; g < G_N; g++)
            if (annb[g * 6 + 5] != -1.0f) has_gt = true;
        float np = (float)s3 + fdn;
        float denom = fmaxf(np, 1.0f);
        res[b][0] = has_gt ? (float)((s0 + dc) / denom) : 0.0f;
        res[b][1] = (has_gt && np > 0.0f) ? (float)((s1 + dr) / (5.0 * denom)) : 0.0f;
        res[b][2] = (has_gt && np > 0.0f) ? (float)((s2 + dl) / (4.0 * denom)) : 0.0f;
    }
    __syncthreads();
    if (tid == 0) {
        out[0] = (res[0][0] + res[1][0]) * 0.5f;
        out[1] = (res[0][1] + res[1][1]) * 0.5f;
        out[2] = (res[0][2] + res[1][2]) * 0.5f;
    }
}

extern "C" void kernel_launch(void* const* d_in, const int* in_sizes, int n_in,
                              void* d_out, int out_size, void* d_ws, size_t ws_size,
                              hipStream_t stream)
{
    (void)in_sizes; (void)n_in; (void)out_size; (void)ws_size;
    const float* cls  = (const float*)d_in[0];
    const float* reg  = (const float*)d_in[1];
    const float* anch = (const float*)d_in[2];
    const float* ann  = (const float*)d_in[3];
    const float* lmk  = (const float*)d_in[4];
    const float* ls   = (const float*)d_in[5];

    char* ws = (char*)d_ws;
    unsigned long long* gtkey = (unsigned long long*)(ws + OFF_GTKEY);
    unsigned long long* akey  = (unsigned long long*)(ws + OFF_AKEY);
    float* partials = (float*)(ws + OFF_PART);
    float* out = (float*)d_out;

    hipMemsetAsync(gtkey, 0, B_N * G_N * 8, stream);
    hipLaunchKernelGGL(k_main, dim3(B_N * BPI), dim3(64), 0, stream,
                       cls, reg, anch, ann, lmk, ls, gtkey, akey, partials);
    hipLaunchKernelGGL(k_fix, dim3(1), dim3(128), 0, stream,
                       cls, reg, anch, ann, lmk, ls, gtkey, akey, partials, out);
}